// Round 2
// baseline (284.815 us; speedup 1.0000x reference)
//
#include <hip/hip_runtime.h>

// x (B=64, C=256, T=2048) fp32; conv_weight (256,256,3); beta (1,); b (256,).
// Output spikes (B,C,T) fp32 in {0,1}. 16384 independent row recurrences ->
// 256 wave64s = 1 wave/CU: the entire LDS (160KB) and VGPR budget per CU is ours.
#define C_DIM 256
#define T_DIM 2048
#define B_DIM 64
#define NROWS (B_DIM * C_DIM)
#define RPB 64                 // rows per block (= wave size)
#define TW 256                 // tile width in floats (1 KB per row per tile)
#define NT (T_DIM / TW)        // 8 tiles
#define RSTRIDE 260            // LDS row stride (floats): 65 granules, odd -> conflict-free b128

__device__ __forceinline__ float sqrn(float v) { return __fmul_rn(v, v); }

// norm[c] = sum of squares of 768 contiguous floats in numpy's exact pairwise
// order (768->384->192->96; 96-blocks via 8-accumulator unrolled loop).
// Verified bit-exact (round-1 absmax 0). DO NOT change the summation tree.
__global__ __launch_bounds__(64) void norm_kernel(const float* __restrict__ w,
                                                  const float* __restrict__ b,
                                                  float* __restrict__ bn,
                                                  float* __restrict__ ninv) {
    const int c = blockIdx.x;
    const int k = threadIdx.x;
    __shared__ float q[8];
    if (k < 8) {
        const float* a = w + c * 768 + k * 96;
        float r0 = sqrn(a[0]), r1 = sqrn(a[1]), r2 = sqrn(a[2]), r3 = sqrn(a[3]);
        float r4 = sqrn(a[4]), r5 = sqrn(a[5]), r6 = sqrn(a[6]), r7 = sqrn(a[7]);
        #pragma unroll
        for (int i = 8; i < 96; i += 8) {
            r0 = __fadd_rn(r0, sqrn(a[i + 0]));
            r1 = __fadd_rn(r1, sqrn(a[i + 1]));
            r2 = __fadd_rn(r2, sqrn(a[i + 2]));
            r3 = __fadd_rn(r3, sqrn(a[i + 3]));
            r4 = __fadd_rn(r4, sqrn(a[i + 4]));
            r5 = __fadd_rn(r5, sqrn(a[i + 5]));
            r6 = __fadd_rn(r6, sqrn(a[i + 6]));
            r7 = __fadd_rn(r7, sqrn(a[i + 7]));
        }
        q[k] = __fadd_rn(__fadd_rn(__fadd_rn(r0, r1), __fadd_rn(r2, r3)),
                         __fadd_rn(__fadd_rn(r4, r5), __fadd_rn(r6, r7)));
    }
    __syncthreads();
    if (k == 0) {
        float s = __fadd_rn(__fadd_rn(__fadd_rn(q[0], q[1]), __fadd_rn(q[2], q[3])),
                            __fadd_rn(__fadd_rn(q[4], q[5]), __fadd_rn(q[6], q[7])));
        bn[c]   = __fmul_rn(b[c], s);
        ninv[c] = 1.0f / __fadd_rn(s, 1e-8f);
    }
}

// LIF step, numpy fp32 semantics: every op separately rounded, no FMA contraction.
__device__ __forceinline__ float lif_step(float xv, float& mem, float& spk,
                                          float bnc, float beta, float omb,
                                          float nic, float bc) {
    float rst  = __fmul_rn(spk, bnc);
    mem        = __fadd_rn(__fmul_rn(__fsub_rn(mem, rst), beta),
                           __fmul_rn(xv, omb));
    float mthr = __fsub_rn(__fmul_rn(mem, nic), bc);
    spk        = (mthr > 0.0f) ? 1.0f : 0.0f;
    return spk;
}

// s_waitcnt immediates (gfx9 encoding: vm[3:0]|exp[6:4]|lgkm[11:8]|vm[5:4]@[15:14])
#define WAITCNT_VM0    0x0F70  // vmcnt(0),  lgkm no-wait
#define WAITCNT_VM62   0xCF7E  // vmcnt(62), lgkm no-wait (62 = max waitable)
#define WAITCNT_LGKM0  0xC07F  // lgkmcnt(0), vm no-wait

#define LDS_PTR(p) ((__attribute__((address_space(3))) void*)(p))
#define GLB_PTR(p) ((const __attribute__((address_space(1))) void*)(p))

// Block = 1 wave = 64 rows. Per tile (64 rows x 256 t):
//   fill : 64x global_load_lds_dwordx4 — each instr = one row's 1 KB, coalesced
//   comp : thread j walks its row in LDS via b128, writes spikes back IN-PLACE
//   drain: lane i reads row r's granule i (b128) -> coalesced 1 KB float4 store
// Double-buffered input tiles; in-place output staging -> 133 KB LDS total.
__global__ __launch_bounds__(64, 1) void lif_kernel(const float* __restrict__ x,
                                                    const float* __restrict__ beta_p,
                                                    const float* __restrict__ b,
                                                    const float* __restrict__ bn,
                                                    const float* __restrict__ ninv,
                                                    float* __restrict__ out) {
    __shared__ __align__(16) float lds[2][RPB * RSTRIDE];

    const int lane = threadIdx.x;           // 0..63
    const int row0 = blockIdx.x * RPB;      // 64 rows per block
    const int c    = (row0 + lane) & (C_DIM - 1);

    const float beta = beta_p[0];
    const float omb  = __fsub_rn(1.0f, beta);
    const float bnc  = bn[c];
    const float nic  = ninv[c];
    const float bc   = b[c];

    // Per-lane global base for DMA fills: lane i covers bytes [16i,16i+16) of a row chunk.
    const float* xbase = x + (size_t)row0 * T_DIM + lane * 4;
    float*       obase = out + (size_t)row0 * T_DIM + lane * 4;

    // Prefetch tile 0 into buffer 0.
    #pragma unroll
    for (int r = 0; r < RPB; ++r) {
        __builtin_amdgcn_global_load_lds(GLB_PTR(xbase + (size_t)r * T_DIM),
                                         LDS_PTR(&lds[0][r * RSTRIDE]), 16, 0, 0);
    }

    float mem = 0.0f, spk = 0.0f;

    #pragma unroll 1
    for (int k = 0; k < NT; ++k) {
        // Wait for this tile's DMA. vmcnt retires in order; at k>0 the 63 newest
        // outstanding ops are prior-tile stores, so vmcnt(62) proves all 64 DMA
        // loads of tile k landed without stalling on store retirement.
        if (k == 0) __builtin_amdgcn_s_waitcnt(WAITCNT_VM0);
        else        __builtin_amdgcn_s_waitcnt(WAITCNT_VM62);

        // Kick off next tile's DMA (issued after the wait so it isn't drained by it).
        if (k + 1 < NT) {
            const float* xt = xbase + (size_t)(k + 1) * TW;
            #pragma unroll
            for (int r = 0; r < RPB; ++r) {
                __builtin_amdgcn_global_load_lds(GLB_PTR(xt + (size_t)r * T_DIM),
                                                 LDS_PTR(&lds[(k + 1) & 1][r * RSTRIDE]),
                                                 16, 0, 0);
            }
        }

        // Compute tile k in-place: row j granule g at float index j*260 + 4g.
        float* buf = &lds[k & 1][0];
        float* myrow = buf + lane * RSTRIDE;
        #pragma unroll 4
        for (int g = 0; g < TW / 4; ++g) {
            float4 v = *(const float4*)(myrow + 4 * g);
            float4 o;
            o.x = lif_step(v.x, mem, spk, bnc, beta, omb, nic, bc);
            o.y = lif_step(v.y, mem, spk, bnc, beta, omb, nic, bc);
            o.z = lif_step(v.z, mem, spk, bnc, beta, omb, nic, bc);
            o.w = lif_step(v.w, mem, spk, bnc, beta, omb, nic, bc);
            *(float4*)(myrow + 4 * g) = o;
        }

        // Cross-lane handoff: lane i will read rows written by other lanes.
        // Same-wave DS ops are processed in order; lgkm drain makes it explicit.
        __builtin_amdgcn_s_waitcnt(WAITCNT_LGKM0);

        // Drain: coalesced 1 KB stores, one row per instruction.
        float* ot = obase + (size_t)k * TW;
        #pragma unroll
        for (int r = 0; r < RPB; ++r) {
            float4 v = *(const float4*)(buf + r * RSTRIDE + 4 * lane);
            *(float4*)(ot + (size_t)r * T_DIM) = v;
        }
    }
}

extern "C" void kernel_launch(void* const* d_in, const int* in_sizes, int n_in,
                              void* d_out, int out_size, void* d_ws, size_t ws_size,
                              hipStream_t stream) {
    const float* x    = (const float*)d_in[0];
    const float* w    = (const float*)d_in[1];
    const float* beta = (const float*)d_in[2];
    const float* b    = (const float*)d_in[3];
    float* out  = (float*)d_out;
    float* bn   = (float*)d_ws;          // 256 floats
    float* ninv = bn + C_DIM;            // 256 floats

    norm_kernel<<<C_DIM, 64, 0, stream>>>(w, b, bn, ninv);
    lif_kernel<<<NROWS / RPB, 64, 0, stream>>>(x, beta, b, bn, ninv, out);
}